// Round 9
// baseline (1026.324 us; speedup 1.0000x reference)
//
#include <hip/hip_runtime.h>
#include <math.h>

#define Hn 50
#define Dn 8
#define Tn 512
#define BB 8               // batches per block
#define NBLK 256           // 2048/8 -> 1 block/CU
#define KST 140            // bP row stride (shorts): 280B/row -> row+8 stride
                           // = 2240B = 560 dw = +16 banks (was 136: 544 dw = 0
                           // mod 32 -> hi/lo write pairs + col/col+8 read pairs
                           // were SAME-BANK). Read b128 coverage stays uniform
                           // (bank starts stride 6 mod 32, all 16 even slots).

typedef __attribute__((ext_vector_type(8))) short short8;   // 8 bf16 (4 VGPRs)
typedef __attribute__((ext_vector_type(4))) float f32x4;

__device__ __forceinline__ float fexp2_(float x) {
#if __has_builtin(__builtin_amdgcn_exp2f)
    return __builtin_amdgcn_exp2f(x);
#else
    return exp2f(x);
#endif
}
__device__ __forceinline__ float frcp_(float x) {
#if __has_builtin(__builtin_amdgcn_rcpf)
    return __builtin_amdgcn_rcpf(x);
#else
    return 1.0f / x;
#endif
}
__device__ __forceinline__ float bf2f(short s) {
    return __uint_as_float(((unsigned)(unsigned short)s) << 16);
}
// truncation split: v = hi + lo + O(2^-17 v)
__device__ __forceinline__ void split_bf(float v, short& hi, short& lo) {
    hi = (short)(__float_as_uint(v) >> 16);
    const float r = v - bf2f(hi);
    lo = (short)(__float_as_uint(r) >> 16);
}
// Pre-scaled act: gates arrive as G = -1.4427*(Wx+b) (i,f,o) / -2.8854*(Wx+b) (g).
// sigmoid(x) = 1/(1+2^G); tanh(x) = 2/(1+2^G) - 1.
__device__ __forceinline__ float lstm_cell4s(const f32x4 g4, float& c) {
    const float si = frcp_(1.0f + fexp2_(g4.x));
    const float sf = frcp_(1.0f + fexp2_(g4.y));
    const float so = frcp_(1.0f + fexp2_(g4.w));
    const float tg = 2.0f * frcp_(1.0f + fexp2_(g4.z)) - 1.0f;
    c = sf * c + si * tg;
    const float tr = frcp_(1.0f + fexp2_(-2.88539008f * c));
    return so * (2.0f * tr - 1.0f);
}
// lane i <-> i^8 via DPP row_ror:8 (16-lane rows): pure VALU, no LDS traffic.
__device__ __forceinline__ float xor8_(float v) {
#if __has_builtin(__builtin_amdgcn_update_dpp)
    return __int_as_float(__builtin_amdgcn_update_dpp(
        0, __float_as_int(v), 0x128 /*row_ror:8*/, 0xF, 0xF, true));
#else
    return __shfl_xor(v, 8, 64);
#endif
}

// ============================================================================
// r21 = r20 with the two suspected-harmful r19 pieces removed + bank fix:
//  - s_setprio REMOVED (m190: setprio hurts barrier-lockstep structures; our
//    16 waves re-converge at one barrier/step — lockstep, not attn-like)
//  - L1 chain back to SINGLE 8-deep accumulate (4 waves/SIMD already hide the
//    chain latency; the split only added merge-adds + register pressure)
//  - KST 136 -> 140: de-aliases the hi/lo write pairs (rows r, r+8) and the
//    col/col+8 read pairs (were 0 mod 32 banks apart; now +16 banks)
// Retained from r18-r20 (theoretically sound, pure instruction-count wins):
//  - DPP xor-8 merge (off the LDS pipe)
//  - act scales folded into weights + bias-in-K + zero-C chain start
// K layout: k 0..49 = h0 | 50..57 = x | 58..62 = 0 | 63 = one | 64..113 = h1 |
//           114..126 = 0 | 127 = one.
// C/D: n=lane&15 (batch: cols 0..7 hi, 8..15 lo), m=(lane>>4)*4+reg = the
// (i,f,g,o) of cell 4T+quad -> act fully in-register.
// ============================================================================

template<int NL1, int NL0, bool XD>
__device__ __forceinline__ void run_loop(
    const int* l1T, const int* l0T,
    int b0, int lane, int quad, int col,
    short (*bP)[16][KST], float* h1f, const float* x,
    const float* Wih0, const float* Whh0, const float* bih0, const float* bhh0,
    const float* Wih1, const float* Whh1, const float* bih1, const float* bhh1)
{
    constexpr int NS = NL1 + NL0;
    constexpr int NPAIR = (NS + 1) / 2;
    constexpr int NBF = (NL1 > 0) ? 4 : 2;

    short8 W1[NL1 > 0 ? NL1 : 1][4][2];   // [slot][kstep][hi/lo]
    short8 W0[NL0 > 0 ? NL0 : 1][2][2];
    int    kb[NS];      // k index base for h-write: layer*64 + 4*T
    int    cellb[NS];   // cell base: 4*T

    // Gate-row scale folded into weights: row's gate type = col&3 (i,f,g,o);
    // g-gate (==2) carries tanh's 2x argument factor.
    const float sc = ((col & 3) == 2) ? -2.88539008f : -1.44269504f;

    // ---- stationary A-side weights: lane holds W[m=col][k=32s+quad*8+j] ----
    #pragma unroll
    for (int i = 0; i < NL1; ++i) {
        const int T = l1T[i];
        const int ng = T * 16 + col, cl = ng >> 2;
        const bool on = (cl < Hn);
        const int grow = (col & 3) * Hn + cl;
        #pragma unroll
        for (int s = 0; s < 4; ++s)
            #pragma unroll
            for (int j = 0; j < 8; ++j) {
                const int k = 32 * s + quad * 8 + j;
                float v = 0.f;
                if (on) {
                    if (k < Hn)                      v = Wih1[grow * Hn + k];
                    else if (k >= 64 && k < 64 + Hn) v = Whh1[grow * Hn + (k - 64)];
                    else if (k == 127)               v = bih1[grow] + bhh1[grow];
                }
                v *= sc;
                short hi, lo; split_bf(v, hi, lo);
                W1[i][s][0][j] = hi; W1[i][s][1][j] = lo;
            }
        kb[i] = 64 + 4 * T; cellb[i] = 4 * T;
    }
    #pragma unroll
    for (int i = 0; i < NL0; ++i) {
        const int T = l0T[i];
        const int ng = T * 16 + col, cl = ng >> 2;
        const bool on = (cl < Hn);
        const int grow = (col & 3) * Hn + cl;
        #pragma unroll
        for (int s = 0; s < 2; ++s)
            #pragma unroll
            for (int j = 0; j < 8; ++j) {
                const int k = 32 * s + quad * 8 + j;
                float v = 0.f;
                if (on) {
                    if (k < Hn)           v = Whh0[grow * Hn + k];
                    else if (k < Hn + Dn) v = Wih0[grow * Dn + (k - Hn)];
                    else if (k == 63)     v = bih0[grow] + bhh0[grow];
                }
                v *= sc;
                short hi, lo; split_bf(v, hi, lo);
                W0[i][s][0][j] = hi; W0[i][s][1][j] = lo;
            }
        kb[NL1 + i] = 4 * T; cellb[NL1 + i] = 4 * T;
    }

    // ---- hoisted loop invariants ----
    const short* base0 = &bP[0][0][0];
    const short* base1 = &bP[1][0][0];
    int rdo[NBF];
    #pragma unroll
    for (int s = 0; s < NBF; ++s) rdo[s] = col * KST + 32 * s + quad * 8;

    int  wofH[NPAIR], wofL[NPAIR], wofS[NPAIR];
    bool actOK[NPAIR], lagged[NPAIR];
    #pragma unroll
    for (int p = 0; p < NPAIR; ++p) {
        const int ia = 2 * p;
        const bool hasB = (ia + 1 < NS);
        const int slot = (hasB && col >= 8) ? ia + 1 : ia;
        const int cell = cellb[slot] + quad;
        const int kc   = kb[slot] + quad;
        lagged[p] = (slot < NL1);
        actOK[p]  = (cell < Hn);
        wofH[p] = (col & 7) * KST + kc;
        wofL[p] = wofH[p] + 8 * KST;
        wofS[p] = col * KST + kc;
    }

    float c[NPAIR];
    #pragma unroll
    for (int p = 0; p < NPAIR; ++p) c[p] = 0.f;
    const f32x4 z4 = {0.f, 0.f, 0.f, 0.f};   // persistent zero C operand

    const float* xp = XD ? (x + (size_t)(b0 + (lane >> 3)) * Tn * Dn + (lane & 7))
                         : (const float*)nullptr;
    int xwH = 0, xwL = 0;
    if (XD) {
        const int xr = lane >> 3, xd = lane & 7;
        xwH = xr * KST + Hn + xd;
        xwL = xwH + 8 * KST;
    }

    // ================= main loop: one phase (one barrier) per timestep ======
    for (int t = 0; t < Tn; ++t) {
        float xv = 0.f;
        if (XD) { if (t + 1 < Tn) xv = xp[(size_t)(t + 1) * Dn]; }   // issue early

        const short* rb = (t & 1) ? base1 : base0;      // scalar selects (t uniform)
        short* wb = (short*)((t & 1) ? base0 : base1);

        // B-side fragments: compile-time order (rule #20: no runtime indexing)
        short8 BF[NBF];
        #pragma unroll
        for (int s = 0; s < NBF; ++s)
            BF[s] = *(const short8*)&rb[rdo[s]];

        f32x4 acc[NS];
        #pragma unroll
        for (int i = 0; i < NL1; ++i) {
            f32x4 a = __builtin_amdgcn_mfma_f32_16x16x32_bf16(W1[i][0][0], BF[0], z4, 0, 0, 0);
            a = __builtin_amdgcn_mfma_f32_16x16x32_bf16(W1[i][0][1], BF[0], a, 0, 0, 0);
            a = __builtin_amdgcn_mfma_f32_16x16x32_bf16(W1[i][1][0], BF[1], a, 0, 0, 0);
            a = __builtin_amdgcn_mfma_f32_16x16x32_bf16(W1[i][1][1], BF[1], a, 0, 0, 0);
            a = __builtin_amdgcn_mfma_f32_16x16x32_bf16(W1[i][2][0], BF[2], a, 0, 0, 0);
            a = __builtin_amdgcn_mfma_f32_16x16x32_bf16(W1[i][2][1], BF[2], a, 0, 0, 0);
            a = __builtin_amdgcn_mfma_f32_16x16x32_bf16(W1[i][3][0], BF[3], a, 0, 0, 0);
            a = __builtin_amdgcn_mfma_f32_16x16x32_bf16(W1[i][3][1], BF[3], a, 0, 0, 0);
            acc[i] = a;
        }
        #pragma unroll
        for (int i = 0; i < NL0; ++i) {
            const int ii = NL1 + i;
            f32x4 a = __builtin_amdgcn_mfma_f32_16x16x32_bf16(W0[i][0][0], BF[0], z4, 0, 0, 0);
            a = __builtin_amdgcn_mfma_f32_16x16x32_bf16(W0[i][0][1], BF[0], a, 0, 0, 0);
            a = __builtin_amdgcn_mfma_f32_16x16x32_bf16(W0[i][1][0], BF[1], a, 0, 0, 0);
            a = __builtin_amdgcn_mfma_f32_16x16x32_bf16(W0[i][1][1], BF[1], a, 0, 0, 0);
            acc[ii] = a;
        }

        // ---- in-register act: paired slots, DPP xor-8 merge ----
        #pragma unroll
        for (int p = 0; p < NPAIR; ++p) {
            const int ia = 2 * p;
            const bool hasB = (ia + 1 < NS);
            f32x4 g;
            #pragma unroll
            for (int r = 0; r < 4; ++r) {
                if (hasB) {
                    const float u = (col < 8) ? acc[ia][r]     : acc[ia + 1][r];
                    const float v = (col < 8) ? acc[ia + 1][r] : acc[ia][r];
                    g[r] = u + xor8_(v);
                } else {
                    g[r] = acc[ia][r] + xor8_(acc[ia][r]);
                }
            }
            const bool doAct = actOK[p] && ((t >= 1) || !lagged[p]);  // L1 lags 1
            if (doAct) {
                const float h = lstm_cell4s(g, c[p]);
                short hi, lo; split_bf(h, hi, lo);
                if (hasB) { wb[wofH[p]] = hi; wb[wofL[p]] = lo; }
                else      { wb[wofS[p]] = (col < 8) ? hi : lo; }
            }
        }
        if (XD) {
            if (t + 1 < Tn) {
                short hi, lo; split_bf(xv, hi, lo);
                wb[xwH] = hi;
                wb[xwL] = lo;
            }
        }
        __syncthreads();
    }

    // ======== epilogue phase: gates1(Tn-1) + act1 -> h1f (fp32) ========
    if constexpr (NL1 > 0) {
        const short* rb = base0;   // Tn even -> bP[0]
        short8 BF[4];
        #pragma unroll
        for (int s = 0; s < 4; ++s)
            BF[s] = *(const short8*)&rb[rdo[s]];
        f32x4 accE[NL1];
        #pragma unroll
        for (int i = 0; i < NL1; ++i) {
            f32x4 a = __builtin_amdgcn_mfma_f32_16x16x32_bf16(W1[i][0][0], BF[0], z4, 0, 0, 0);
            a = __builtin_amdgcn_mfma_f32_16x16x32_bf16(W1[i][0][1], BF[0], a, 0, 0, 0);
            a = __builtin_amdgcn_mfma_f32_16x16x32_bf16(W1[i][1][0], BF[1], a, 0, 0, 0);
            a = __builtin_amdgcn_mfma_f32_16x16x32_bf16(W1[i][1][1], BF[1], a, 0, 0, 0);
            a = __builtin_amdgcn_mfma_f32_16x16x32_bf16(W1[i][2][0], BF[2], a, 0, 0, 0);
            a = __builtin_amdgcn_mfma_f32_16x16x32_bf16(W1[i][2][1], BF[2], a, 0, 0, 0);
            a = __builtin_amdgcn_mfma_f32_16x16x32_bf16(W1[i][3][0], BF[3], a, 0, 0, 0);
            a = __builtin_amdgcn_mfma_f32_16x16x32_bf16(W1[i][3][1], BF[3], a, 0, 0, 0);
            accE[i] = a;
        }
        #pragma unroll
        for (int p = 0; p < NPAIR; ++p) {
            const int ia = 2 * p;
            if (ia < NL1) {
                const bool bL1 = (ia + 1 < NL1);
                f32x4 g;
                #pragma unroll
                for (int r = 0; r < 4; ++r) {
                    if (bL1) {
                        const float u = (col < 8) ? accE[ia][r]     : accE[ia + 1][r];
                        const float v = (col < 8) ? accE[ia + 1][r] : accE[ia][r];
                        g[r] = u + xor8_(v);
                    } else {
                        g[r] = accE[ia][r] + xor8_(accE[ia][r]);
                    }
                }
                int cell; bool mine;
                if (bL1) { cell = ((col < 8) ? cellb[ia] : cellb[ia + 1]) + quad; mine = true; }
                else     { cell = cellb[ia] + quad;                               mine = (col < 8); }
                if (mine && cell < Hn) {
                    const float h = lstm_cell4s(g, c[p]);
                    h1f[cell * 8 + (col & 7)] = h;
                }
            }
        }
    }
}

__global__ __launch_bounds__(1024) void lstm2_kernel(
    const float* __restrict__ x,
    const float* __restrict__ Wih0, const float* __restrict__ Whh0,
    const float* __restrict__ bih0, const float* __restrict__ bhh0,
    const float* __restrict__ Wih1, const float* __restrict__ Whh1,
    const float* __restrict__ bih1, const float* __restrict__ bhh1,
    const float* __restrict__ Wlin, const float* __restrict__ blin,
    float* __restrict__ out)
{
    const int tid  = threadIdx.x;     // 0..1023
    const int b0   = blockIdx.x * BB;
    // readfirstlane: wave index SGPR-uniform so shape dispatch is scalar —
    // __syncthreads lives inside the branches (equal counts in all arms).
    const int w    = __builtin_amdgcn_readfirstlane(tid >> 6);   // 0..15
    const int lane = tid & 63;
    const int quad = lane >> 4;
    const int col  = lane & 15;

    __shared__ __align__(16) short bP[2][16][KST];   // double-buffered h/x pack
    __shared__ float h1f[Hn * 8];                    // fp32 h1 at t=Tn-1

    // ---- init: zero both buffers; plant bias-ones; stage x(0) ----
    for (int i = tid; i < 2 * 16 * KST; i += 1024) (&bP[0][0][0])[i] = 0;
    __syncthreads();
    if (tid < 8) {               // bf16(1.0) at k=63 / k=127, hi rows only
        const short one = (short)0x3F80;
        bP[0][tid][63]  = one;  bP[1][tid][63]  = one;
        bP[0][tid][127] = one;  bP[1][tid][127] = one;
    } else if (tid >= 64 && tid < 128) {
        const int q = tid - 64;
        const int xb = q >> 3, xd = q & 7;
        const float f = x[((size_t)(b0 + xb) * Tn + 0) * Dn + xd];
        short hi, lo; split_bf(f, hi, lo);
        bP[0][xb][Hn + xd]     = hi;
        bP[0][xb + 8][Hn + xd] = lo;
    }
    __syncthreads();

    // 16 waves, wave i -> SIMD i&3: mixed short/long MFMA bursts per SIMD.
    // Per-SIMD MFMA totals: 40/40/40/36.
    if (w < 8) {
        const int l1t[1] = {w};
        const int l0t[1] = {w};
        run_loop<1, 1, false>(l1t, l0t, b0, lane, quad, col, bP, h1f, x,
                              Wih0, Whh0, bih0, bhh0, Wih1, Whh1, bih1, bhh1);
    } else if (w < 13) {
        const int l1t[1] = {w};      // L1 tiles 8..12
        run_loop<1, 0, false>(l1t, nullptr, b0, lane, quad, col, bP, h1f, x,
                              Wih0, Whh0, bih0, bhh0, Wih1, Whh1, bih1, bhh1);
    } else if (w == 13) {
        const int l0t[2] = {8, 9};
        run_loop<0, 2, false>(nullptr, l0t, b0, lane, quad, col, bP, h1f, x,
                              Wih0, Whh0, bih0, bhh0, Wih1, Whh1, bih1, bhh1);
    } else if (w == 14) {
        const int l0t[2] = {10, 11};
        run_loop<0, 2, false>(nullptr, l0t, b0, lane, quad, col, bP, h1f, x,
                              Wih0, Whh0, bih0, bhh0, Wih1, Whh1, bih1, bhh1);
    } else {
        const int l0t[1] = {12};
        run_loop<0, 1, true>(nullptr, l0t, b0, lane, quad, col, bP, h1f, x,
                             Wih0, Whh0, bih0, bhh0, Wih1, Whh1, bih1, bhh1);
    }
    __syncthreads();

    // ---- head: out[b] = h1_last . Wlin + blin (fp32 path) ----
    if (tid < BB) {
        float o = blin[0];
        #pragma unroll
        for (int k = 0; k < Hn; ++k) o += Wlin[k] * h1f[k * 8 + tid];
        out[b0 + tid] = o;
    }
}

extern "C" void kernel_launch(void* const* d_in, const int* in_sizes, int n_in,
                              void* d_out, int out_size, void* d_ws, size_t ws_size,
                              hipStream_t stream) {
    const float* x    = (const float*)d_in[0];
    const float* Wih0 = (const float*)d_in[1];
    const float* Whh0 = (const float*)d_in[2];
    const float* bih0 = (const float*)d_in[3];
    const float* bhh0 = (const float*)d_in[4];
    const float* Wih1 = (const float*)d_in[5];
    const float* Whh1 = (const float*)d_in[6];
    const float* bih1 = (const float*)d_in[7];
    const float* bhh1 = (const float*)d_in[8];
    const float* Wlin = (const float*)d_in[9];
    const float* blin = (const float*)d_in[10];
    float* out = (float*)d_out;

    lstm2_kernel<<<NBLK, 1024, 0, stream>>>(x, Wih0, Whh0, bih0, bhh0,
                                            Wih1, Whh1, bih1, bhh1,
                                            Wlin, blin, out);
}

// Round 10
// 458.322 us; speedup vs baseline: 2.2393x; 2.2393x over previous
//
#include <hip/hip_runtime.h>
#include <math.h>

#define Hn 50
#define Dn 8
#define Tn 512
#define BB 8               // batches per block
#define NBLK 256           // 2048/8 -> 1 block/CU
#define KST 136            // row stride (shorts). MUST be ==0 mod 8 shorts: b128
                           // reads at col*KST need 16B alignment (r21: KST=140
                           // broke it -> split loads, 2.4x slowdown). Bank alias
                           // of row+8 (0 mod 32) is accepted: conflicts are
                           // ~274 cy/CU/step, not the wall.

typedef __attribute__((ext_vector_type(8))) short short8;   // 8 bf16 (4 VGPRs)
typedef __attribute__((ext_vector_type(4))) float f32x4;

__device__ __forceinline__ float fexp2_(float x) {
#if __has_builtin(__builtin_amdgcn_exp2f)
    return __builtin_amdgcn_exp2f(x);
#else
    return exp2f(x);
#endif
}
__device__ __forceinline__ float frcp_(float x) {
#if __has_builtin(__builtin_amdgcn_rcpf)
    return __builtin_amdgcn_rcpf(x);
#else
    return 1.0f / x;
#endif
}
__device__ __forceinline__ float bf2f(short s) {
    return __uint_as_float(((unsigned)(unsigned short)s) << 16);
}
// truncation split: v = hi + lo + O(2^-17 v)
__device__ __forceinline__ void split_bf(float v, short& hi, short& lo) {
    hi = (short)(__float_as_uint(v) >> 16);
    const float r = v - bf2f(hi);
    lo = (short)(__float_as_uint(r) >> 16);
}
// Pre-scaled act: gates arrive as G = -1.4427*(Wx+b) (i,f,o) / -2.8854*(Wx+b) (g).
// sigmoid(x) = 1/(1+2^G); tanh(x) = 2/(1+2^G) - 1.
__device__ __forceinline__ float lstm_cell4s(const f32x4 g4, float& c) {
    const float si = frcp_(1.0f + fexp2_(g4.x));
    const float sf = frcp_(1.0f + fexp2_(g4.y));
    const float so = frcp_(1.0f + fexp2_(g4.w));
    const float tg = 2.0f * frcp_(1.0f + fexp2_(g4.z)) - 1.0f;
    c = sf * c + si * tg;
    const float tr = frcp_(1.0f + fexp2_(-2.88539008f * c));
    return so * (2.0f * tr - 1.0f);
}
// lane i <-> i^8 via DPP row_ror:8 (16-lane rows): pure VALU, no LDS traffic.
__device__ __forceinline__ float xor8_(float v) {
#if __has_builtin(__builtin_amdgcn_update_dpp)
    return __int_as_float(__builtin_amdgcn_update_dpp(
        0, __float_as_int(v), 0x128 /*row_ror:8*/, 0xF, 0xF, true));
#else
    return __shfl_xor(v, 8, 64);
#endif
}

// ============================================================================
// r22: CONSOLIDATED SLOT MAP to shrink the post-barrier LDS read convoy.
// r20 analysis: no pipe saturated; the dominant serial block is all
// L1-carrying waves re-reading the ENTIRE 4KB h-pack each step. Read volume
// is per-wave (NBF), independent of slot count -> pack L1 into fewer waves:
//   w0-5 : 2 L1 slots   (NBF=4, 4KB/step)   16 MFMA
//   w6   : 1 L1 + 1 L0  (NBF=4, 4KB)        12 MFMA
//   w7-12: 2 L0 slots   (NBF=2, 2KB)         8 MFMA
//   w13  : x-duty only  (no LDS reads)
//   w14/15: idle (barrier-only)
// Total read 40KB/step vs r20's 58KB (-31%). Worst-wave VGPR ~105 < 128 cap
// (4 waves/SIMD). Reverted: KST=140 (r21: misaligned b128, 2.4x), setprio
// (m190: hurts lockstep), chain-split (no effect at 4 waves/SIMD).
// Kept from r18-r20: DPP xor-8 merge, act scales folded into weights,
// bias-in-K (bf16 1.0 at k=63/127), zero-C chain start, KST=136.
// K layout: k 0..49 = h0 | 50..57 = x | 58..62 = 0 | 63 = one | 64..113 = h1 |
//           114..126 = 0 | 127 = one.
// C/D: n=lane&15 (batch: cols 0..7 hi, 8..15 lo), m=(lane>>4)*4+reg = the
// (i,f,g,o) of cell 4T+quad -> act fully in-register.
// ============================================================================

template<int NL1, int NL0, bool XD>
__device__ __forceinline__ void run_loop(
    const int* l1T, const int* l0T,
    int b0, int lane, int quad, int col,
    short (*bP)[16][KST], float* h1f, const float* x,
    const float* Wih0, const float* Whh0, const float* bih0, const float* bhh0,
    const float* Wih1, const float* Whh1, const float* bih1, const float* bhh1)
{
    constexpr int NS = NL1 + NL0;
    constexpr int NPAIR = (NS + 1) / 2;
    constexpr int NBF = (NL1 > 0) ? 4 : 2;
    constexpr int NSg = (NS > 0) ? NS : 1;       // zero-size array guards
    constexpr int NPg = (NPAIR > 0) ? NPAIR : 1;

    short8 W1[NL1 > 0 ? NL1 : 1][4][2];   // [slot][kstep][hi/lo]
    short8 W0[NL0 > 0 ? NL0 : 1][2][2];
    int    kb[NSg];      // k index base for h-write: layer*64 + 4*T
    int    cellb[NSg];   // cell base: 4*T

    // Gate-row scale folded into weights: row's gate type = col&3 (i,f,g,o);
    // g-gate (==2) carries tanh's 2x argument factor.
    const float sc = ((col & 3) == 2) ? -2.88539008f : -1.44269504f;

    // ---- stationary A-side weights: lane holds W[m=col][k=32s+quad*8+j] ----
    #pragma unroll
    for (int i = 0; i < NL1; ++i) {
        const int T = l1T[i];
        const int ng = T * 16 + col, cl = ng >> 2;
        const bool on = (cl < Hn);
        const int grow = (col & 3) * Hn + cl;
        #pragma unroll
        for (int s = 0; s < 4; ++s)
            #pragma unroll
            for (int j = 0; j < 8; ++j) {
                const int k = 32 * s + quad * 8 + j;
                float v = 0.f;
                if (on) {
                    if (k < Hn)                      v = Wih1[grow * Hn + k];
                    else if (k >= 64 && k < 64 + Hn) v = Whh1[grow * Hn + (k - 64)];
                    else if (k == 127)               v = bih1[grow] + bhh1[grow];
                }
                v *= sc;
                short hi, lo; split_bf(v, hi, lo);
                W1[i][s][0][j] = hi; W1[i][s][1][j] = lo;
            }
        kb[i] = 64 + 4 * T; cellb[i] = 4 * T;
    }
    #pragma unroll
    for (int i = 0; i < NL0; ++i) {
        const int T = l0T[i];
        const int ng = T * 16 + col, cl = ng >> 2;
        const bool on = (cl < Hn);
        const int grow = (col & 3) * Hn + cl;
        #pragma unroll
        for (int s = 0; s < 2; ++s)
            #pragma unroll
            for (int j = 0; j < 8; ++j) {
                const int k = 32 * s + quad * 8 + j;
                float v = 0.f;
                if (on) {
                    if (k < Hn)           v = Whh0[grow * Hn + k];
                    else if (k < Hn + Dn) v = Wih0[grow * Dn + (k - Hn)];
                    else if (k == 63)     v = bih0[grow] + bhh0[grow];
                }
                v *= sc;
                short hi, lo; split_bf(v, hi, lo);
                W0[i][s][0][j] = hi; W0[i][s][1][j] = lo;
            }
        kb[NL1 + i] = 4 * T; cellb[NL1 + i] = 4 * T;
    }

    // ---- hoisted loop invariants ----
    const short* base0 = &bP[0][0][0];
    const short* base1 = &bP[1][0][0];
    int rdo[NBF];
    #pragma unroll
    for (int s = 0; s < NBF; ++s) rdo[s] = col * KST + 32 * s + quad * 8;

    int  wofH[NPg], wofL[NPg], wofS[NPg];
    bool actOK[NPg], lagged[NPg];
    #pragma unroll
    for (int p = 0; p < NPAIR; ++p) {
        const int ia = 2 * p;
        const bool hasB = (ia + 1 < NS);
        const int slot = (hasB && col >= 8) ? ia + 1 : ia;
        const int cell = cellb[slot] + quad;
        const int kc   = kb[slot] + quad;
        lagged[p] = (slot < NL1);
        actOK[p]  = (cell < Hn);
        wofH[p] = (col & 7) * KST + kc;
        wofL[p] = wofH[p] + 8 * KST;
        wofS[p] = col * KST + kc;
    }

    float c[NPg];
    #pragma unroll
    for (int p = 0; p < NPg; ++p) c[p] = 0.f;
    const f32x4 z4 = {0.f, 0.f, 0.f, 0.f};   // persistent zero C operand

    const float* xp = XD ? (x + (size_t)(b0 + (lane >> 3)) * Tn * Dn + (lane & 7))
                         : (const float*)nullptr;
    int xwH = 0, xwL = 0;
    if (XD) {
        const int xr = lane >> 3, xd = lane & 7;
        xwH = xr * KST + Hn + xd;
        xwL = xwH + 8 * KST;
    }

    // ================= main loop: one phase (one barrier) per timestep ======
    for (int t = 0; t < Tn; ++t) {
        float xv = 0.f;
        if (XD) { if (t + 1 < Tn) xv = xp[(size_t)(t + 1) * Dn]; }   // issue early

        const short* rb = (t & 1) ? base1 : base0;      // scalar selects (t uniform)
        short* wb = (short*)((t & 1) ? base0 : base1);

        if constexpr (NS > 0) {
            // B-side fragments: compile-time order (rule #20: no runtime idx)
            short8 BF[NBF];
            #pragma unroll
            for (int s = 0; s < NBF; ++s)
                BF[s] = *(const short8*)&rb[rdo[s]];

            f32x4 acc[NSg];
            #pragma unroll
            for (int i = 0; i < NL1; ++i) {
                f32x4 a = __builtin_amdgcn_mfma_f32_16x16x32_bf16(W1[i][0][0], BF[0], z4, 0, 0, 0);
                a = __builtin_amdgcn_mfma_f32_16x16x32_bf16(W1[i][0][1], BF[0], a, 0, 0, 0);
                a = __builtin_amdgcn_mfma_f32_16x16x32_bf16(W1[i][1][0], BF[1], a, 0, 0, 0);
                a = __builtin_amdgcn_mfma_f32_16x16x32_bf16(W1[i][1][1], BF[1], a, 0, 0, 0);
                a = __builtin_amdgcn_mfma_f32_16x16x32_bf16(W1[i][2][0], BF[2], a, 0, 0, 0);
                a = __builtin_amdgcn_mfma_f32_16x16x32_bf16(W1[i][2][1], BF[2], a, 0, 0, 0);
                a = __builtin_amdgcn_mfma_f32_16x16x32_bf16(W1[i][3][0], BF[3], a, 0, 0, 0);
                a = __builtin_amdgcn_mfma_f32_16x16x32_bf16(W1[i][3][1], BF[3], a, 0, 0, 0);
                acc[i] = a;
            }
            #pragma unroll
            for (int i = 0; i < NL0; ++i) {
                const int ii = NL1 + i;
                f32x4 a = __builtin_amdgcn_mfma_f32_16x16x32_bf16(W0[i][0][0], BF[0], z4, 0, 0, 0);
                a = __builtin_amdgcn_mfma_f32_16x16x32_bf16(W0[i][0][1], BF[0], a, 0, 0, 0);
                a = __builtin_amdgcn_mfma_f32_16x16x32_bf16(W0[i][1][0], BF[1], a, 0, 0, 0);
                a = __builtin_amdgcn_mfma_f32_16x16x32_bf16(W0[i][1][1], BF[1], a, 0, 0, 0);
                acc[ii] = a;
            }

            // ---- in-register act: paired slots, DPP xor-8 merge ----
            #pragma unroll
            for (int p = 0; p < NPAIR; ++p) {
                const int ia = 2 * p;
                const bool hasB = (ia + 1 < NS);
                f32x4 g;
                #pragma unroll
                for (int r = 0; r < 4; ++r) {
                    if (hasB) {
                        const float u = (col < 8) ? acc[ia][r]     : acc[ia + 1][r];
                        const float v = (col < 8) ? acc[ia + 1][r] : acc[ia][r];
                        g[r] = u + xor8_(v);
                    } else {
                        g[r] = acc[ia][r] + xor8_(acc[ia][r]);
                    }
                }
                const bool doAct = actOK[p] && ((t >= 1) || !lagged[p]);  // L1 lags 1
                if (doAct) {
                    const float h = lstm_cell4s(g, c[p]);
                    short hi, lo; split_bf(h, hi, lo);
                    if (hasB) { wb[wofH[p]] = hi; wb[wofL[p]] = lo; }
                    else      { wb[wofS[p]] = (col < 8) ? hi : lo; }
                }
            }
        }
        if (XD) {
            if (t + 1 < Tn) {
                short hi, lo; split_bf(xv, hi, lo);
                wb[xwH] = hi;
                wb[xwL] = lo;
            }
        }
        __syncthreads();
    }

    // ======== epilogue phase: gates1(Tn-1) + act1 -> h1f (fp32) ========
    if constexpr (NL1 > 0) {
        const short* rb = base0;   // Tn even -> bP[0]
        short8 BF[4];
        #pragma unroll
        for (int s = 0; s < 4; ++s)
            BF[s] = *(const short8*)&rb[rdo[s]];
        f32x4 accE[NL1];
        #pragma unroll
        for (int i = 0; i < NL1; ++i) {
            f32x4 a = __builtin_amdgcn_mfma_f32_16x16x32_bf16(W1[i][0][0], BF[0], z4, 0, 0, 0);
            a = __builtin_amdgcn_mfma_f32_16x16x32_bf16(W1[i][0][1], BF[0], a, 0, 0, 0);
            a = __builtin_amdgcn_mfma_f32_16x16x32_bf16(W1[i][1][0], BF[1], a, 0, 0, 0);
            a = __builtin_amdgcn_mfma_f32_16x16x32_bf16(W1[i][1][1], BF[1], a, 0, 0, 0);
            a = __builtin_amdgcn_mfma_f32_16x16x32_bf16(W1[i][2][0], BF[2], a, 0, 0, 0);
            a = __builtin_amdgcn_mfma_f32_16x16x32_bf16(W1[i][2][1], BF[2], a, 0, 0, 0);
            a = __builtin_amdgcn_mfma_f32_16x16x32_bf16(W1[i][3][0], BF[3], a, 0, 0, 0);
            a = __builtin_amdgcn_mfma_f32_16x16x32_bf16(W1[i][3][1], BF[3], a, 0, 0, 0);
            accE[i] = a;
        }
        #pragma unroll
        for (int p = 0; p < NPAIR; ++p) {
            const int ia = 2 * p;
            if (ia < NL1) {
                const bool bL1 = (ia + 1 < NL1);
                f32x4 g;
                #pragma unroll
                for (int r = 0; r < 4; ++r) {
                    if (bL1) {
                        const float u = (col < 8) ? accE[ia][r]     : accE[ia + 1][r];
                        const float v = (col < 8) ? accE[ia + 1][r] : accE[ia][r];
                        g[r] = u + xor8_(v);
                    } else {
                        g[r] = accE[ia][r] + xor8_(accE[ia][r]);
                    }
                }
                int cell; bool mine;
                if (bL1) { cell = ((col < 8) ? cellb[ia] : cellb[ia + 1]) + quad; mine = true; }
                else     { cell = cellb[ia] + quad;                               mine = (col < 8); }
                if (mine && cell < Hn) {
                    const float h = lstm_cell4s(g, c[p]);
                    h1f[cell * 8 + (col & 7)] = h;
                }
            }
        }
    }
}

__global__ __launch_bounds__(1024) void lstm2_kernel(
    const float* __restrict__ x,
    const float* __restrict__ Wih0, const float* __restrict__ Whh0,
    const float* __restrict__ bih0, const float* __restrict__ bhh0,
    const float* __restrict__ Wih1, const float* __restrict__ Whh1,
    const float* __restrict__ bih1, const float* __restrict__ bhh1,
    const float* __restrict__ Wlin, const float* __restrict__ blin,
    float* __restrict__ out)
{
    const int tid  = threadIdx.x;     // 0..1023
    const int b0   = blockIdx.x * BB;
    // readfirstlane: wave index SGPR-uniform so shape dispatch is scalar —
    // __syncthreads lives inside the branches (equal counts in all arms).
    const int w    = __builtin_amdgcn_readfirstlane(tid >> 6);   // 0..15
    const int lane = tid & 63;
    const int quad = lane >> 4;
    const int col  = lane & 15;

    __shared__ __align__(16) short bP[2][16][KST];   // double-buffered h/x pack
    __shared__ float h1f[Hn * 8];                    // fp32 h1 at t=Tn-1

    // ---- init: zero both buffers; plant bias-ones; stage x(0) ----
    for (int i = tid; i < 2 * 16 * KST; i += 1024) (&bP[0][0][0])[i] = 0;
    __syncthreads();
    if (tid < 8) {               // bf16(1.0) at k=63 / k=127, hi rows only
        const short one = (short)0x3F80;
        bP[0][tid][63]  = one;  bP[1][tid][63]  = one;
        bP[0][tid][127] = one;  bP[1][tid][127] = one;
    } else if (tid >= 64 && tid < 128) {
        const int q = tid - 64;
        const int xb = q >> 3, xd = q & 7;
        const float f = x[((size_t)(b0 + xb) * Tn + 0) * Dn + xd];
        short hi, lo; split_bf(f, hi, lo);
        bP[0][xb][Hn + xd]     = hi;
        bP[0][xb + 8][Hn + xd] = lo;
    }
    __syncthreads();

    // Consolidated map: 6A (2L1) + 1B (1L1+1L0) + 6C (2L0) + XD + 2 idle.
    // Per-SIMD MFMA (w->SIMD w&3): 48/40/36/32 — matrix pipe not binding.
    if (w < 6) {
        const int l1t[2] = {2 * w, 2 * w + 1};       // L1 tiles 0..11
        run_loop<2, 0, false>(l1t, nullptr, b0, lane, quad, col, bP, h1f, x,
                              Wih0, Whh0, bih0, bhh0, Wih1, Whh1, bih1, bhh1);
    } else if (w == 6) {
        const int l1t[1] = {12};                     // L1 tile 12
        const int l0t[1] = {0};                      // L0 tile 0
        run_loop<1, 1, false>(l1t, l0t, b0, lane, quad, col, bP, h1f, x,
                              Wih0, Whh0, bih0, bhh0, Wih1, Whh1, bih1, bhh1);
    } else if (w < 13) {
        const int l0t[2] = {2 * (w - 7) + 1, 2 * (w - 7) + 2};   // L0 1..12
        run_loop<0, 2, false>(nullptr, l0t, b0, lane, quad, col, bP, h1f, x,
                              Wih0, Whh0, bih0, bhh0, Wih1, Whh1, bih1, bhh1);
    } else if (w == 13) {
        run_loop<0, 0, true>(nullptr, nullptr, b0, lane, quad, col, bP, h1f, x,
                             Wih0, Whh0, bih0, bhh0, Wih1, Whh1, bih1, bhh1);
    } else {
        run_loop<0, 0, false>(nullptr, nullptr, b0, lane, quad, col, bP, h1f, x,
                              Wih0, Whh0, bih0, bhh0, Wih1, Whh1, bih1, bhh1);
    }
    __syncthreads();

    // ---- head: out[b] = h1_last . Wlin + blin (fp32 path) ----
    if (tid < BB) {
        float o = blin[0];
        #pragma unroll
        for (int k = 0; k < Hn; ++k) o += Wlin[k] * h1f[k * 8 + tid];
        out[b0 + tid] = o;
    }
}

extern "C" void kernel_launch(void* const* d_in, const int* in_sizes, int n_in,
                              void* d_out, int out_size, void* d_ws, size_t ws_size,
                              hipStream_t stream) {
    const float* x    = (const float*)d_in[0];
    const float* Wih0 = (const float*)d_in[1];
    const float* Whh0 = (const float*)d_in[2];
    const float* bih0 = (const float*)d_in[3];
    const float* bhh0 = (const float*)d_in[4];
    const float* Wih1 = (const float*)d_in[5];
    const float* Whh1 = (const float*)d_in[6];
    const float* bih1 = (const float*)d_in[7];
    const float* bhh1 = (const float*)d_in[8];
    const float* Wlin = (const float*)d_in[9];
    const float* blin = (const float*)d_in[10];
    float* out = (float*)d_out;

    lstm2_kernel<<<NBLK, 1024, 0, stream>>>(x, Wih0, Whh0, bih0, bhh0,
                                            Wih1, Whh1, bih1, bhh1,
                                            Wlin, blin, out);
}

// Round 11
// 406.170 us; speedup vs baseline: 2.5268x; 1.1284x over previous
//
#include <hip/hip_runtime.h>
#include <math.h>

#define Hn 50
#define Dn 8
#define Tn 512
#define BB 8               // batches per block
#define NBLK 256           // 2048/8 -> 1 block/CU
#define KST 136            // row stride (shorts). MUST be 0 mod 8 (16B-aligned
                           // b128 reads; r21's KST=140 split every load, 2.4x).
                           // row+8 bank alias accepted: conflicts not the wall
                           // (r22: -41% conflicts, +4% time).

typedef __attribute__((ext_vector_type(8))) short short8;   // 8 bf16 (4 VGPRs)
typedef __attribute__((ext_vector_type(4))) float f32x4;

__device__ __forceinline__ float fexp2_(float x) {
#if __has_builtin(__builtin_amdgcn_exp2f)
    return __builtin_amdgcn_exp2f(x);
#else
    return exp2f(x);
#endif
}
__device__ __forceinline__ float frcp_(float x) {
#if __has_builtin(__builtin_amdgcn_rcpf)
    return __builtin_amdgcn_rcpf(x);
#else
    return 1.0f / x;
#endif
}
__device__ __forceinline__ float bf2f(short s) {
    return __uint_as_float(((unsigned)(unsigned short)s) << 16);
}
// truncation split: v = hi + lo + O(2^-17 v)
__device__ __forceinline__ void split_bf(float v, short& hi, short& lo) {
    hi = (short)(__float_as_uint(v) >> 16);
    const float r = v - bf2f(hi);
    lo = (short)(__float_as_uint(r) >> 16);
}
// Pre-scaled act: gates arrive as G = -1.4427*(Wx+b) (i,f,o) / -2.8854*(Wx+b) (g).
// sigmoid(x) = 1/(1+2^G); tanh(x) = 2/(1+2^G) - 1.
__device__ __forceinline__ float lstm_cell4s(const f32x4 g4, float& c) {
    const float si = frcp_(1.0f + fexp2_(g4.x));
    const float sf = frcp_(1.0f + fexp2_(g4.y));
    const float so = frcp_(1.0f + fexp2_(g4.w));
    const float tg = 2.0f * frcp_(1.0f + fexp2_(g4.z)) - 1.0f;
    c = sf * c + si * tg;
    const float tr = frcp_(1.0f + fexp2_(-2.88539008f * c));
    return so * (2.0f * tr - 1.0f);
}
// lane i <-> i^8 via DPP row_ror:8 (16-lane rows): pure VALU, no LDS traffic.
__device__ __forceinline__ float xor8_(float v) {
#if __has_builtin(__builtin_amdgcn_update_dpp)
    return __int_as_float(__builtin_amdgcn_update_dpp(
        0, __float_as_int(v), 0x128 /*row_ror:8*/, 0xF, 0xF, true));
#else
    return __shfl_xor(v, 8, 64);
#endif
}

// ============================================================================
// r23 = the UNTESTED clean combination: r17's slot map (best measured, 405us)
// + instruction-diet only.
// History: r20 = diet + setprio + chain-split (416); r21 = + misaligned KST
// (1004); r22 = diet + consolidated map, compiler spilled at 64-VGPR budget
// (434, WRITE_SIZE 2.7MB, LDS +8K). Never measured: diet alone on r17's map.
//  - slot map w0-7: 1L1+1L0 | w8-12: 1L1 | w13: L0{8,9} | w14: L0{10,11} |
//    w15: L0{12}+x. Per-SIMD MFMA 40/40/40/36; max weight regs/wave = 48.
//  - __launch_bounds__(1024, 4): pins 4 waves/SIMD -> 128-VGPR budget, so the
//    compiler cannot target 2-block occupancy and spill (r22's failure).
//  - NO setprio (m190: costs ~1.5% in barrier-lockstep), NO chain-split.
//  - Diet: DPP xor-8 merge; act scales folded into weights; bias-in-K (bf16
//    1.0 at k=63/127, bias row in W); zero-C chain start.
// K layout: k 0..49 = h0 | 50..57 = x | 58..62 = 0 | 63 = one | 64..113 = h1 |
//           114..126 = 0 | 127 = one.
// C/D: n=lane&15 (batch: cols 0..7 hi, 8..15 lo), m=(lane>>4)*4+reg = the
// (i,f,g,o) of cell 4T+quad -> act fully in-register.
// ============================================================================

template<int NL1, int NL0, bool XD>
__device__ __forceinline__ void run_loop(
    const int* l1T, const int* l0T,
    int b0, int lane, int quad, int col,
    short (*bP)[16][KST], float* h1f, const float* x,
    const float* Wih0, const float* Whh0, const float* bih0, const float* bhh0,
    const float* Wih1, const float* Whh1, const float* bih1, const float* bhh1)
{
    constexpr int NS = NL1 + NL0;
    constexpr int NPAIR = (NS + 1) / 2;
    constexpr int NBF = (NL1 > 0) ? 4 : 2;

    short8 W1[NL1 > 0 ? NL1 : 1][4][2];   // [slot][kstep][hi/lo]
    short8 W0[NL0 > 0 ? NL0 : 1][2][2];
    int    kb[NS];      // k index base for h-write: layer*64 + 4*T
    int    cellb[NS];   // cell base: 4*T

    // Gate-row scale folded into weights: row's gate type = col&3 (i,f,g,o);
    // g-gate (==2) carries tanh's 2x argument factor.
    const float sc = ((col & 3) == 2) ? -2.88539008f : -1.44269504f;

    // ---- stationary A-side weights: lane holds W[m=col][k=32s+quad*8+j] ----
    #pragma unroll
    for (int i = 0; i < NL1; ++i) {
        const int T = l1T[i];
        const int ng = T * 16 + col, cl = ng >> 2;
        const bool on = (cl < Hn);
        const int grow = (col & 3) * Hn + cl;
        #pragma unroll
        for (int s = 0; s < 4; ++s)
            #pragma unroll
            for (int j = 0; j < 8; ++j) {
                const int k = 32 * s + quad * 8 + j;
                float v = 0.f;
                if (on) {
                    if (k < Hn)                      v = Wih1[grow * Hn + k];
                    else if (k >= 64 && k < 64 + Hn) v = Whh1[grow * Hn + (k - 64)];
                    else if (k == 127)               v = bih1[grow] + bhh1[grow];
                }
                v *= sc;
                short hi, lo; split_bf(v, hi, lo);
                W1[i][s][0][j] = hi; W1[i][s][1][j] = lo;
            }
        kb[i] = 64 + 4 * T; cellb[i] = 4 * T;
    }
    #pragma unroll
    for (int i = 0; i < NL0; ++i) {
        const int T = l0T[i];
        const int ng = T * 16 + col, cl = ng >> 2;
        const bool on = (cl < Hn);
        const int grow = (col & 3) * Hn + cl;
        #pragma unroll
        for (int s = 0; s < 2; ++s)
            #pragma unroll
            for (int j = 0; j < 8; ++j) {
                const int k = 32 * s + quad * 8 + j;
                float v = 0.f;
                if (on) {
                    if (k < Hn)           v = Whh0[grow * Hn + k];
                    else if (k < Hn + Dn) v = Wih0[grow * Dn + (k - Hn)];
                    else if (k == 63)     v = bih0[grow] + bhh0[grow];
                }
                v *= sc;
                short hi, lo; split_bf(v, hi, lo);
                W0[i][s][0][j] = hi; W0[i][s][1][j] = lo;
            }
        kb[NL1 + i] = 4 * T; cellb[NL1 + i] = 4 * T;
    }

    // ---- hoisted loop invariants ----
    const short* base0 = &bP[0][0][0];
    const short* base1 = &bP[1][0][0];
    int rdo[NBF];
    #pragma unroll
    for (int s = 0; s < NBF; ++s) rdo[s] = col * KST + 32 * s + quad * 8;

    int  wofH[NPAIR], wofL[NPAIR], wofS[NPAIR];
    bool actOK[NPAIR], lagged[NPAIR];
    #pragma unroll
    for (int p = 0; p < NPAIR; ++p) {
        const int ia = 2 * p;
        const bool hasB = (ia + 1 < NS);
        const int slot = (hasB && col >= 8) ? ia + 1 : ia;
        const int cell = cellb[slot] + quad;
        const int kc   = kb[slot] + quad;
        lagged[p] = (slot < NL1);
        actOK[p]  = (cell < Hn);
        wofH[p] = (col & 7) * KST + kc;
        wofL[p] = wofH[p] + 8 * KST;
        wofS[p] = col * KST + kc;
    }

    float c[NPAIR];
    #pragma unroll
    for (int p = 0; p < NPAIR; ++p) c[p] = 0.f;
    const f32x4 z4 = {0.f, 0.f, 0.f, 0.f};   // persistent zero C operand

    const float* xp = XD ? (x + (size_t)(b0 + (lane >> 3)) * Tn * Dn + (lane & 7))
                         : (const float*)nullptr;
    int xwH = 0, xwL = 0;
    if (XD) {
        const int xr = lane >> 3, xd = lane & 7;
        xwH = xr * KST + Hn + xd;
        xwL = xwH + 8 * KST;
    }

    // ================= main loop: one phase (one barrier) per timestep ======
    for (int t = 0; t < Tn; ++t) {
        float xv = 0.f;
        if (XD) { if (t + 1 < Tn) xv = xp[(size_t)(t + 1) * Dn]; }   // issue early

        const short* rb = (t & 1) ? base1 : base0;      // scalar selects (t uniform)
        short* wb = (short*)((t & 1) ? base0 : base1);

        // B-side fragments: compile-time order (rule #20: no runtime indexing)
        short8 BF[NBF];
        #pragma unroll
        for (int s = 0; s < NBF; ++s)
            BF[s] = *(const short8*)&rb[rdo[s]];

        f32x4 acc[NS];
        #pragma unroll
        for (int i = 0; i < NL1; ++i) {
            f32x4 a = __builtin_amdgcn_mfma_f32_16x16x32_bf16(W1[i][0][0], BF[0], z4, 0, 0, 0);
            a = __builtin_amdgcn_mfma_f32_16x16x32_bf16(W1[i][0][1], BF[0], a, 0, 0, 0);
            a = __builtin_amdgcn_mfma_f32_16x16x32_bf16(W1[i][1][0], BF[1], a, 0, 0, 0);
            a = __builtin_amdgcn_mfma_f32_16x16x32_bf16(W1[i][1][1], BF[1], a, 0, 0, 0);
            a = __builtin_amdgcn_mfma_f32_16x16x32_bf16(W1[i][2][0], BF[2], a, 0, 0, 0);
            a = __builtin_amdgcn_mfma_f32_16x16x32_bf16(W1[i][2][1], BF[2], a, 0, 0, 0);
            a = __builtin_amdgcn_mfma_f32_16x16x32_bf16(W1[i][3][0], BF[3], a, 0, 0, 0);
            a = __builtin_amdgcn_mfma_f32_16x16x32_bf16(W1[i][3][1], BF[3], a, 0, 0, 0);
            acc[i] = a;
        }
        #pragma unroll
        for (int i = 0; i < NL0; ++i) {
            const int ii = NL1 + i;
            f32x4 a = __builtin_amdgcn_mfma_f32_16x16x32_bf16(W0[i][0][0], BF[0], z4, 0, 0, 0);
            a = __builtin_amdgcn_mfma_f32_16x16x32_bf16(W0[i][0][1], BF[0], a, 0, 0, 0);
            a = __builtin_amdgcn_mfma_f32_16x16x32_bf16(W0[i][1][0], BF[1], a, 0, 0, 0);
            a = __builtin_amdgcn_mfma_f32_16x16x32_bf16(W0[i][1][1], BF[1], a, 0, 0, 0);
            acc[ii] = a;
        }

        // ---- in-register act: paired slots, DPP xor-8 merge ----
        #pragma unroll
        for (int p = 0; p < NPAIR; ++p) {
            const int ia = 2 * p;
            const bool hasB = (ia + 1 < NS);
            f32x4 g;
            #pragma unroll
            for (int r = 0; r < 4; ++r) {
                if (hasB) {
                    const float u = (col < 8) ? acc[ia][r]     : acc[ia + 1][r];
                    const float v = (col < 8) ? acc[ia + 1][r] : acc[ia][r];
                    g[r] = u + xor8_(v);
                } else {
                    g[r] = acc[ia][r] + xor8_(acc[ia][r]);
                }
            }
            const bool doAct = actOK[p] && ((t >= 1) || !lagged[p]);  // L1 lags 1
            if (doAct) {
                const float h = lstm_cell4s(g, c[p]);
                short hi, lo; split_bf(h, hi, lo);
                if (hasB) { wb[wofH[p]] = hi; wb[wofL[p]] = lo; }
                else      { wb[wofS[p]] = (col < 8) ? hi : lo; }
            }
        }
        if (XD) {
            if (t + 1 < Tn) {
                short hi, lo; split_bf(xv, hi, lo);
                wb[xwH] = hi;
                wb[xwL] = lo;
            }
        }
        __syncthreads();
    }

    // ======== epilogue phase: gates1(Tn-1) + act1 -> h1f (fp32) ========
    if constexpr (NL1 > 0) {
        const short* rb = base0;   // Tn even -> bP[0]
        short8 BF[4];
        #pragma unroll
        for (int s = 0; s < 4; ++s)
            BF[s] = *(const short8*)&rb[rdo[s]];
        f32x4 accE[NL1];
        #pragma unroll
        for (int i = 0; i < NL1; ++i) {
            f32x4 a = __builtin_amdgcn_mfma_f32_16x16x32_bf16(W1[i][0][0], BF[0], z4, 0, 0, 0);
            a = __builtin_amdgcn_mfma_f32_16x16x32_bf16(W1[i][0][1], BF[0], a, 0, 0, 0);
            a = __builtin_amdgcn_mfma_f32_16x16x32_bf16(W1[i][1][0], BF[1], a, 0, 0, 0);
            a = __builtin_amdgcn_mfma_f32_16x16x32_bf16(W1[i][1][1], BF[1], a, 0, 0, 0);
            a = __builtin_amdgcn_mfma_f32_16x16x32_bf16(W1[i][2][0], BF[2], a, 0, 0, 0);
            a = __builtin_amdgcn_mfma_f32_16x16x32_bf16(W1[i][2][1], BF[2], a, 0, 0, 0);
            a = __builtin_amdgcn_mfma_f32_16x16x32_bf16(W1[i][3][0], BF[3], a, 0, 0, 0);
            a = __builtin_amdgcn_mfma_f32_16x16x32_bf16(W1[i][3][1], BF[3], a, 0, 0, 0);
            accE[i] = a;
        }
        #pragma unroll
        for (int p = 0; p < NPAIR; ++p) {
            const int ia = 2 * p;
            if (ia < NL1) {
                const bool bL1 = (ia + 1 < NL1);
                f32x4 g;
                #pragma unroll
                for (int r = 0; r < 4; ++r) {
                    if (bL1) {
                        const float u = (col < 8) ? accE[ia][r]     : accE[ia + 1][r];
                        const float v = (col < 8) ? accE[ia + 1][r] : accE[ia][r];
                        g[r] = u + xor8_(v);
                    } else {
                        g[r] = accE[ia][r] + xor8_(accE[ia][r]);
                    }
                }
                int cell; bool mine;
                if (bL1) { cell = ((col < 8) ? cellb[ia] : cellb[ia + 1]) + quad; mine = true; }
                else     { cell = cellb[ia] + quad;                               mine = (col < 8); }
                if (mine && cell < Hn) {
                    const float h = lstm_cell4s(g, c[p]);
                    h1f[cell * 8 + (col & 7)] = h;
                }
            }
        }
    }
}

__global__ __launch_bounds__(1024, 4) void lstm2_kernel(
    const float* __restrict__ x,
    const float* __restrict__ Wih0, const float* __restrict__ Whh0,
    const float* __restrict__ bih0, const float* __restrict__ bhh0,
    const float* __restrict__ Wih1, const float* __restrict__ Whh1,
    const float* __restrict__ bih1, const float* __restrict__ bhh1,
    const float* __restrict__ Wlin, const float* __restrict__ blin,
    float* __restrict__ out)
{
    const int tid  = threadIdx.x;     // 0..1023
    const int b0   = blockIdx.x * BB;
    // readfirstlane: wave index SGPR-uniform so shape dispatch is scalar —
    // __syncthreads lives inside the branches (equal counts in all arms).
    const int w    = __builtin_amdgcn_readfirstlane(tid >> 6);   // 0..15
    const int lane = tid & 63;
    const int quad = lane >> 4;
    const int col  = lane & 15;

    __shared__ __align__(16) short bP[2][16][KST];   // double-buffered h/x pack
    __shared__ float h1f[Hn * 8];                    // fp32 h1 at t=Tn-1

    // ---- init: zero both buffers; plant bias-ones; stage x(0) ----
    for (int i = tid; i < 2 * 16 * KST; i += 1024) (&bP[0][0][0])[i] = 0;
    __syncthreads();
    if (tid < 8) {               // bf16(1.0) at k=63 / k=127, hi rows only
        const short one = (short)0x3F80;
        bP[0][tid][63]  = one;  bP[1][tid][63]  = one;
        bP[0][tid][127] = one;  bP[1][tid][127] = one;
    } else if (tid >= 64 && tid < 128) {
        const int q = tid - 64;
        const int xb = q >> 3, xd = q & 7;
        const float f = x[((size_t)(b0 + xb) * Tn + 0) * Dn + xd];
        short hi, lo; split_bf(f, hi, lo);
        bP[0][xb][Hn + xd]     = hi;
        bP[0][xb + 8][Hn + xd] = lo;
    }
    __syncthreads();

    // r17's slot map (best measured): 16 waves, wave i -> SIMD i&3.
    // Per-SIMD MFMA totals: 40/40/40/36; max weight regs/wave = 48.
    if (w < 8) {
        const int l1t[1] = {w};
        const int l0t[1] = {w};
        run_loop<1, 1, false>(l1t, l0t, b0, lane, quad, col, bP, h1f, x,
                              Wih0, Whh0, bih0, bhh0, Wih1, Whh1, bih1, bhh1);
    } else if (w < 13) {
        const int l1t[1] = {w};      // L1 tiles 8..12
        run_loop<1, 0, false>(l1t, nullptr, b0, lane, quad, col, bP, h1f, x,
                              Wih0, Whh0, bih0, bhh0, Wih1, Whh1, bih1, bhh1);
    } else if (w == 13) {
        const int l0t[2] = {8, 9};
        run_loop<0, 2, false>(nullptr, l0t, b0, lane, quad, col, bP, h1f, x,
                              Wih0, Whh0, bih0, bhh0, Wih1, Whh1, bih1, bhh1);
    } else if (w == 14) {
        const int l0t[2] = {10, 11};
        run_loop<0, 2, false>(nullptr, l0t, b0, lane, quad, col, bP, h1f, x,
                              Wih0, Whh0, bih0, bhh0, Wih1, Whh1, bih1, bhh1);
    } else {
        const int l0t[1] = {12};
        run_loop<0, 1, true>(nullptr, l0t, b0, lane, quad, col, bP, h1f, x,
                             Wih0, Whh0, bih0, bhh0, Wih1, Whh1, bih1, bhh1);
    }
    __syncthreads();

    // ---- head: out[b] = h1_last . Wlin + blin (fp32 path) ----
    if (tid < BB) {
        float o = blin[0];
        #pragma unroll
        for (int k = 0; k < Hn; ++k) o += Wlin[k] * h1f[k * 8 + tid];
        out[b0 + tid] = o;
    }
}

extern "C" void kernel_launch(void* const* d_in, const int* in_sizes, int n_in,
                              void* d_out, int out_size, void* d_ws, size_t ws_size,
                              hipStream_t stream) {
    const float* x    = (const float*)d_in[0];
    const float* Wih0 = (const float*)d_in[1];
    const float* Whh0 = (const float*)d_in[2];
    const float* bih0 = (const float*)d_in[3];
    const float* bhh0 = (const float*)d_in[4];
    const float* Wih1 = (const float*)d_in[5];
    const float* Whh1 = (const float*)d_in[6];
    const float* bih1 = (const float*)d_in[7];
    const float* bhh1 = (const float*)d_in[8];
    const float* Wlin = (const float*)d_in[9];
    const float* blin = (const float*)d_in[10];
    float* out = (float*)d_out;

    lstm2_kernel<<<NBLK, 1024, 0, stream>>>(x, Wih0, Whh0, bih0, bhh0,
                                            Wih1, Whh1, bih1, bhh1,
                                            Wlin, blin, out);
}